// Round 5
// baseline (161.159 us; speedup 1.0000x reference)
//
#include <hip/hip_runtime.h>
#include <hip/hip_bf16.h>

typedef __attribute__((ext_vector_type(8))) short short8;
typedef __attribute__((ext_vector_type(4))) float float4v;
typedef __attribute__((ext_vector_type(2))) float float2v;
typedef __attribute__((ext_vector_type(4))) unsigned uint4v;

#define S_A 0.04419417382415922f   // 1/(16*sqrt(2)) : a2, and a1*s2
#define S_B 0.025515518153991442f  // 1/(16*sqrt(6)) : a2/sqrt(3), and a1/sqrt(6)
#define S_C 0.0625f                // 1/16 : a1

// Pack two fp32 -> two bf16 (RNE) in one dword: low = a, high = b.
static __device__ __forceinline__ unsigned pkbf(float a, float b) {
#if __has_builtin(__builtin_amdgcn_cvt_pk_bf16_f32)
    auto v = __builtin_amdgcn_cvt_pk_bf16_f32(a, b);   // v_cvt_pk_bf16_f32 (gfx950)
    return __builtin_bit_cast(unsigned, v);
#else
    unsigned ua = __builtin_bit_cast(unsigned, a);
    unsigned ub = __builtin_bit_cast(unsigned, b);
    ua += 0x7fffu + ((ua >> 16) & 1u);                 // RNE
    ub += 0x7fffu + ((ub >> 16) & 1u);
    return __builtin_amdgcn_perm(ub, ua, 0x07060302);  // {hi16(ub), hi16(ua)}
#endif
}

// ---- Prep: W (5 x 16^3 fp32) -> bf16 in MFMA B-fragment layout in d_ws ----
// path ids after reorder: 0=w0, 1=w2, 2=w1, 3=w3, 4=w4
// addr: k=c*32+kk, lane=(kk>>3)*16+w, j=kk&7 -> wout[((c*5+p)*64+lane)*8+j]
__global__ void wprep_kernel(const float* __restrict__ wA, const float* __restrict__ wB,
                             const float* __restrict__ wC, const float* __restrict__ wD,
                             const float* __restrict__ wE, unsigned short* __restrict__ wout)
{
    int e = blockIdx.x * 256 + threadIdx.x;
    if (e >= 5 * 4096) return;
    int p = e >> 12;
    int rem = e & 4095;                    // rem = k*16 + w
    const float* wp = (p == 0) ? wA : (p == 1) ? wB : (p == 2) ? wC : (p == 3) ? wD : wE;
    unsigned u = __builtin_bit_cast(unsigned, wp[rem]);
    u += 0x7fffu + ((u >> 16) & 1u);       // RNE to bf16
    int k = rem >> 4, w = rem & 15;
    int c = k >> 5, kk = k & 31;
    int lane = ((kk >> 3) << 4) | w;
    int j = kk & 7;
    wout[(((c * 5 + p) * 64 + lane) << 3) | j] = (unsigned short)(u >> 16);
}

// Single-wave blocks, wave-specialized by m-group, TWO 16-row tiles per wave.
// Groups (disjoint output dwords):
//   G0: m{2,3,4}     (1o)           path w1
//   G1: m{0,1,10,12} (0e + 2e diag) paths w0,w2,w4
//   G2: m{5,6,7}     (1e)           path w3
//   G3: m{8,9,11}    (2e off-diag)  path w4
// A-frag: lane l holds A[row=l&15][k=c*32+(l>>4)*8+j]; B-frag: W[k][w=l&15]
// C/D: lane l, reg r -> D[row=(l>>4)*4+r][col=l&15]
template<int G>
static __device__ __forceinline__ void run_group(
    const float* __restrict__ xlds, int l, const short8* __restrict__ wbase,
    float* __restrict__ out, long long z0, int nrows)
{
    const int r  = l & 15;
    const int g  = l >> 4;
    const int v0 = (g & 1) * 8;
    const int uo = g >> 1;

    const float* xr0 = xlds + r * 68;
    const float* xr1 = xlds + (16 + r) * 68;

    // v-side cache (float2 over cell pairs 2t, 2t+1), per tile
    float2v Xv[2][4], Yv[2][4], Zv[2][4];
    float2v A0v[2][4];
    #pragma unroll
    for (int T = 0; T < 2; T++) {
        const float* xr = T ? xr1 : xr0;
        float b[24];
        #pragma unroll
        for (int q = 0; q < 6; q++)
            *(float4v*)&b[q * 4] = *(const float4v*)(xr + 16 + v0 * 3 + q * 4);
        #pragma unroll
        for (int t = 0; t < 4; t++) {
            Xv[T][t] = (float2v){b[6 * t + 0], b[6 * t + 3]};
            Yv[T][t] = (float2v){b[6 * t + 1], b[6 * t + 4]};
            Zv[T][t] = (float2v){b[6 * t + 2], b[6 * t + 5]};
        }
        if constexpr (G == 1) {
            float a[8];
            #pragma unroll
            for (int q = 0; q < 2; q++)
                *(float4v*)&a[q * 4] = *(const float4v*)(xr + v0 + q * 4);
            #pragma unroll
            for (int t = 0; t < 4; t++) A0v[T][t] = (float2v){a[2 * t], a[2 * t + 1]};
        }
    }

    constexpr int NS = (G == 1) ? 4 : 3;
    float4v acc[2][NS];
    #pragma unroll
    for (int T = 0; T < 2; T++)
        #pragma unroll
        for (int s = 0; s < NS; s++) acc[T][s] = (float4v){0.f, 0.f, 0.f, 0.f};

    #pragma unroll
    for (int c = 0; c < 8; c++) {
        // B-fragments for this chunk (L2-resident, coalesced dwordx4) — shared by both tiles
        short8 wfA, wfB, wfC;
        if constexpr (G == 0) wfA = wbase[(c * 5 + 2) * 64 + l];
        if constexpr (G == 1) {
            wfA = wbase[(c * 5 + 0) * 64 + l];
            wfB = wbase[(c * 5 + 1) * 64 + l];
            wfC = wbase[(c * 5 + 4) * 64 + l];
        }
        if constexpr (G == 2) wfA = wbase[(c * 5 + 3) * 64 + l];
        if constexpr (G == 3) wfA = wbase[(c * 5 + 4) * 64 + l];

        const int u = c * 2 + uo;

        #pragma unroll
        for (int T = 0; T < 2; T++) {
            const float* xr = T ? xr1 : xr0;
            float u0 = 0.f, ux = 0.f, uy = 0.f, uz = 0.f;
            if constexpr (G == 0 || G == 1) u0 = xr[u];
            if constexpr (G != 0) {
                ux = xr[16 + u * 3 + 0];
                uy = xr[16 + u * 3 + 1];
                uz = xr[16 + u * 3 + 2];
            }

            unsigned fri[NS][4];
            #pragma unroll
            for (int t = 0; t < 4; t++) {
                const float2v X = Xv[T][t], Y = Yv[T][t], Z = Zv[T][t];
                if constexpr (G == 0) {
                    float2v b2 = u0 * X, b3 = u0 * Y, b4 = u0 * Z;
                    fri[0][t] = pkbf(b2.x, b2.y);
                    fri[1][t] = pkbf(b3.x, b3.y);
                    fri[2][t] = pkbf(b4.x, b4.y);
                }
                if constexpr (G == 1) {
                    float2v p00 = ux * X, p11 = uy * Y, p22 = uz * Z;
                    float2v b0 = u0 * A0v[T][t];
                    float2v b1 = p00 + p11 + p22;
                    float2v b10 = 2.0f * p22 - p00 - p11;
                    float2v b12 = p00 - p11;
                    fri[0][t] = pkbf(b0.x, b0.y);
                    fri[1][t] = pkbf(b1.x, b1.y);
                    fri[2][t] = pkbf(b10.x, b10.y);
                    fri[3][t] = pkbf(b12.x, b12.y);
                }
                if constexpr (G == 2) {
                    float2v p01 = ux * Y, p02 = ux * Z, p10 = uy * X;
                    float2v p12 = uy * Z, p20 = uz * X, p21 = uz * Y;
                    float2v b5 = p12 - p21, b6 = p20 - p02, b7 = p01 - p10;
                    fri[0][t] = pkbf(b5.x, b5.y);
                    fri[1][t] = pkbf(b6.x, b6.y);
                    fri[2][t] = pkbf(b7.x, b7.y);
                }
                if constexpr (G == 3) {
                    float2v p01 = ux * Y, p02 = ux * Z, p10 = uy * X;
                    float2v p12 = uy * Z, p20 = uz * X, p21 = uz * Y;
                    float2v b8 = p01 + p10, b9 = p12 + p21, b11 = p02 + p20;
                    fri[0][t] = pkbf(b8.x, b8.y);
                    fri[1][t] = pkbf(b9.x, b9.y);
                    fri[2][t] = pkbf(b11.x, b11.y);
                }
            }

            #pragma unroll
            for (int s = 0; s < NS; s++) {
                short8 frm = __builtin_bit_cast(short8, *(uint4v*)fri[s]);
                const short8& wf = (G == 1) ? ((s == 0) ? wfA : (s == 1) ? wfB : wfC) : wfA;
                acc[T][s] = __builtin_amdgcn_mfma_f32_16x16x32_bf16(frm, wf, acc[T][s], 0, 0, 0);
            }
        }
    }

    // ---- Epilogue: scale + store. w = l&15, rows z0 + T*16 + g*4 + reg ----
    const int w = r;
    #pragma unroll
    for (int T = 0; T < 2; T++) {
        float* outp = out + (z0 + T * 16 + g * 4) * 192;
        #pragma unroll
        for (int reg = 0; reg < 4; reg++) {
            if (z0 + T * 16 + g * 4 + reg >= nrows) break;
            float* rowp = outp + reg * 192;
            if constexpr (G == 0) {
                rowp[16 + w * 3 + 0] = S_C * acc[T][0][reg];
                rowp[16 + w * 3 + 1] = S_C * acc[T][1][reg];
                rowp[16 + w * 3 + 2] = S_C * acc[T][2][reg];
            }
            if constexpr (G == 1) {
                rowp[w]               = S_A * acc[T][0][reg] + S_B * acc[T][1][reg];
                rowp[112 + w * 5 + 2] = S_B * acc[T][2][reg];
                rowp[112 + w * 5 + 4] = S_A * acc[T][3][reg];
            }
            if constexpr (G == 2) {
                rowp[64 + w * 3 + 0] = S_A * acc[T][0][reg];
                rowp[64 + w * 3 + 1] = S_A * acc[T][1][reg];
                rowp[64 + w * 3 + 2] = S_A * acc[T][2][reg];
            }
            if constexpr (G == 3) {
                rowp[112 + w * 5 + 0] = S_A * acc[T][0][reg];
                rowp[112 + w * 5 + 1] = S_A * acc[T][1][reg];
                rowp[112 + w * 5 + 3] = S_A * acc[T][2][reg];
            }
        }
    }
}

__global__ __launch_bounds__(64)
void tsq_kernel(const float* __restrict__ x,
                const unsigned short* __restrict__ wfrag,
                float* __restrict__ out,
                int nrows)
{
    // one 32-row z-tile per (single-wave) block; stride 68 keeps aliasing at free 2-way
    __shared__ __attribute__((aligned(16))) float xlds[32 * 68];

    const int l = threadIdx.x;
    const int bid = blockIdx.x;
    const int grp = bid & 3;
    const long long z0 = (long long)(bid >> 2) * 32;

    // stage 32 rows x 64 floats (8 x coalesced 1KB float4 loads)
    {
        const float* xg = x + z0 * 64;
        #pragma unroll
        for (int q = 0; q < 8; q++) {
            int e = q * 64 + l;                 // float4 index
            int row = e >> 4, col = (e & 15) * 4;
            float4v v = {0.f, 0.f, 0.f, 0.f};
            if (z0 + row < nrows) v = *(const float4v*)(xg + e * 4);
            *(float4v*)&xlds[row * 68 + col] = v;
        }
    }
    __syncthreads();   // single wave: cheap; orders LDS writes vs cross-lane reads
    if (z0 >= nrows) return;

    const short8* wbase = (const short8*)wfrag;

    if      (grp == 0) run_group<0>(xlds, l, wbase, out, z0, nrows);
    else if (grp == 1) run_group<1>(xlds, l, wbase, out, z0, nrows);
    else if (grp == 2) run_group<2>(xlds, l, wbase, out, z0, nrows);
    else               run_group<3>(xlds, l, wbase, out, z0, nrows);
}

extern "C" void kernel_launch(void* const* d_in, const int* in_sizes, int n_in,
                              void* d_out, int out_size, void* d_ws, size_t ws_size,
                              hipStream_t stream) {
    const float* x  = (const float*)d_in[0];
    const float* w0 = (const float*)d_in[1];
    const float* w1 = (const float*)d_in[2];
    const float* w2 = (const float*)d_in[3];
    const float* w3 = (const float*)d_in[4];
    const float* w4 = (const float*)d_in[5];
    float* out = (float*)d_out;
    unsigned short* wfrag = (unsigned short*)d_ws;   // 40 KB used
    (void)ws_size; (void)n_in; (void)out_size;

    const int nrows = in_sizes[0] / 64;              // 100000
    const int ntiles = (nrows + 31) / 32;            // 3125
    const int nblocks = ntiles * 4;                  // 12500 (tile-major: 4 groups adjacent)

    // path order: {w0, w2, w1, w3, w4}
    wprep_kernel<<<dim3(80), dim3(256), 0, stream>>>(w0, w2, w1, w3, w4, wfrag);
    tsq_kernel<<<dim3(nblocks), dim3(64), 0, stream>>>(x, wfrag, out, nrows);
}